// Round 4
// baseline (176.841 us; speedup 1.0000x reference)
//
#include <hip/hip_runtime.h>
#include <hip/hip_bf16.h>

#define NUM_CLASSES 32000
#define EMBED 128
#define NTOK (64 * 4096)
#define CLS_PER_BLK 64

// ---------------------------------------------------------------------------
// Kernel 1: bias-fused transpose (all f32).
//   Wb[c*128 + e] = W[e*32000 + c] + b[e]
// Tile: 64 classes x 128 embed per block, LDS staged, stride 65 to avoid
// bank conflicts on the transposed read.
// ---------------------------------------------------------------------------
__global__ __launch_bounds__(256) void build_table_kernel(
    const float* __restrict__ W,
    const float* __restrict__ bias,
    float* __restrict__ Wb) {
  __shared__ float lds[EMBED * (CLS_PER_BLK + 1)];

  const int c0  = blockIdx.x * CLS_PER_BLK;
  const int tid = threadIdx.x;

  // Load phase: coalesced along classes (64 lanes x 4B = 256B rows).
  const int tx = tid & 63;   // class-in-tile
  const int ty = tid >> 6;   // 0..3
  for (int e = ty; e < EMBED; e += 4) {
    lds[e * (CLS_PER_BLK + 1) + tx] = W[(size_t)e * NUM_CLASSES + c0 + tx];
  }
  __syncthreads();

  // Store phase: coalesced along embed (contiguous 512B f32 rows).
  const int e    = tid & 127;
  const int half = tid >> 7;  // 0..1
  const float bv = bias[e];
  for (int ci = half; ci < CLS_PER_BLK; ci += 2) {
    Wb[(size_t)(c0 + ci) * EMBED + e] = lds[e * (CLS_PER_BLK + 1) + ci] + bv;
  }
}

// ---------------------------------------------------------------------------
// Kernel 2: gather rows of Wb at (int32) token indices. 32 threads/token,
// 16B float4 per thread. Writes: perfectly coalesced (134MB). Reads:
// 512B-contiguous random rows of a 16MB table (L2/L3 resident).
// ---------------------------------------------------------------------------
__global__ __launch_bounds__(256) void gather_kernel(
    const int* __restrict__ x,
    const float* __restrict__ Wb,
    float* __restrict__ out) {
  const int g     = blockIdx.x * 256 + threadIdx.x;
  const int token = g >> 5;   // 32 float4 lanes per token (128 f32)
  const int j     = g & 31;
  const int c     = x[token];
  reinterpret_cast<float4*>(out)[g] =
      reinterpret_cast<const float4*>(Wb)[(size_t)c * 32 + j];
}

// ---------------------------------------------------------------------------
// Fallback (workspace too small): direct scattered gather from W.
// ---------------------------------------------------------------------------
__global__ __launch_bounds__(256) void direct_kernel(
    const int* __restrict__ x,
    const float* __restrict__ W,
    const float* __restrict__ bias,
    float* __restrict__ out) {
  const int g     = blockIdx.x * 256 + threadIdx.x;
  const int token = g >> 7;
  const int e     = g & 127;
  const int c     = x[token];
  out[g] = W[(size_t)e * NUM_CLASSES + c] + bias[e];
}

extern "C" void kernel_launch(void* const* d_in, const int* in_sizes, int n_in,
                              void* d_out, int out_size, void* d_ws, size_t ws_size,
                              hipStream_t stream) {
  const int*   x    = (const int*)d_in[0];
  const float* W    = (const float*)d_in[1];
  const float* bias = (const float*)d_in[2];
  float*       out  = (float*)d_out;

  const size_t table_bytes = (size_t)NUM_CLASSES * EMBED * sizeof(float);

  if (ws_size >= table_bytes) {
    float* Wb = (float*)d_ws;
    build_table_kernel<<<NUM_CLASSES / CLS_PER_BLK, 256, 0, stream>>>(W, bias, Wb);
    gather_kernel<<<(NTOK * 32) / 256, 256, 0, stream>>>(x, Wb, out);
  } else {
    direct_kernel<<<(NTOK * EMBED) / 256, 256, 0, stream>>>(x, W, bias, out);
  }
}